// Round 7
// baseline (395.527 us; speedup 1.0000x reference)
//
#include <hip/hip_runtime.h>

#define NIMG 16
#define NC 3
#define H 256
#define W 256
#define HW (H * W)
#define NS 25           // 5x5 per-pixel kernel
#define TH 16
#define TW 16
#define SRH (TH + 10)   // 26 s-region rows (fac halo 2 + conv halo 3 each side)
#define SRC (TW + 10)   // 26 s-region valid cols
#define SRW 28          // LDS row stride in float2 (even -> float4-aliasable)
#define SRN (SRH * SRW)
#define MRH (TH + 4)    // 20 q-region rows (fac halo 2 each side)
#define MRW (TW + 4)    // 20
#define MRN (MRH * MRW) // 400
#define NPAIR (MRN / 2) // 200 conv point-pairs
#define NTHREADS 256
#define NHALO (SRH * SRC - TH * TW)  // 420 halo-only region points

// Fused kernel, v6: LDS-pipe fix.
// v5 rocprof: 200us, VALU 41%, HBM 12%, bank-conflict 15M cyc. DS-instr
// audit: phase2 = 49 s_l b32 + ~98 wts b32 per point, phase3 = 75 b32
// -> ~310 DS ops/thread/branch ~= 100us/CU on the one LDS pipe = the wall.
// Fixes (DS ops ~310 -> ~60 per thread per branch):
//  1. conv weights read from GLOBAL with uniform index -> s_load (scalar
//     cache), zero DS. 1/25 mean-fold moved into phase-1 (sum*0.04).
//  2. s_l = fp32 float2 (avg,max), stride 28; phase 2 does a 1x2 point
//     PAIR per thread: 7 rows x 4 ds_read_b128 = 28 b128 per pair
//     (was ~76 b32 + 2 unpack VALU per tap). fp32 also beats bf16 precision.
//  3. q interleaved [MRN]{c0,c1,c2,pad}: phase 3 = 26 ds_read_b128 with
//     immediate offsets (was 75 b32); phase 2 writes 1 b128 per point.
//  - pk[25] register cache unchanged (phase 3 still zero global loads).
//  - launch_bounds(256,2) = proven 128-VGPR no-spill budget (WRITE_SIZE
//    ~13MB is the no-spill tell; v3/v4 spilled at 40/64 VGPR).
//  - XCD-chunked swizzle, bijective (4096 % 8 == 0).
__global__ __launch_bounds__(NTHREADS, 2)
void reblur_fused(const float* __restrict__ blur_info,
                  const float* __restrict__ pp0,
                  const float* __restrict__ pp1,
                  const float* __restrict__ pp2,
                  const float* __restrict__ wt0,
                  const float* __restrict__ wt1,
                  const float* __restrict__ wt2,
                  float* __restrict__ out)
{
    __shared__ __attribute__((aligned(16))) float2 s_l[SRN];  // 5.8 KB (avg,max) fp32
    __shared__ float4 q4[MRN];                                // 6.4 KB {q0,q1,q2,pad}

    const int tid = threadIdx.x;

    // XCD-chunked swizzle: 4096 blocks, 512 contiguous tiles per XCD.
    const int id  = blockIdx.x + (blockIdx.y << 4) + (blockIdx.z << 8);
    const int sid = ((id & 7) << 9) + (id >> 3);
    const int n   = sid >> 8;
    const int h0  = ((sid >> 4) & 15) * TH;
    const int w0  = (sid & 15) * TW;

    float facc0 = 0.f, facc1 = 0.f, facc2 = 0.f;

    const size_t nbase = (size_t)n * NS * HW;
    const int r = tid >> 4, c = tid & 15;          // this thread's center pixel

    float pk[NS];   // statically indexed only -> stays in VGPRs

    #pragma unroll 1
    for (int b = 0; b < 3; ++b) {
        const float* pb = (b == 0) ? pp0 : ((b == 1) ? pp1 : pp2);
        const float* wb = (b == 0) ? wt0 : ((b == 1) ? wt1 : wt2);
        pb += nbase;

        // ---- phase 1a: center 16x16 — stream 25 ch, reduce AND keep in regs
        {
            const float* p = pb + (h0 + r) * W + (w0 + c);
            float v = p[0];
            pk[0] = v;
            float sm = v, mx = v;
            #pragma unroll
            for (int s = 1; s < NS; ++s) {
                v = p[s * HW];
                pk[s] = v;
                sm += v; mx = fmaxf(mx, v);
            }
            s_l[(r + 5) * SRW + (c + 5)] = make_float2(sm * 0.04f, mx);
        }

        // ---- phase 1b: halo-only points (420) — reduce, no storage
        for (int m = tid; m < NHALO; m += NTHREADS) {
            int rr, cc;
            if (m < 130)      { rr = m / 26;              cc = m % 26; }
            else if (m < 260) { int t = m - 130; rr = 21 + t / 26; cc = t % 26; }
            else              { int t = m - 260; rr = 5 + t / 10;
                                int c2 = t % 10; cc = (c2 < 5) ? c2 : c2 + 16; }
            const int gh = h0 - 5 + rr, gw = w0 - 5 + cc;
            float2 u = make_float2(0.f, 0.f);      // zero-pad of [avg,max]
            if ((unsigned)gh < H && (unsigned)gw < W) {
                const float* p = pb + gh * W + gw;
                float v = p[0];
                float sm = v, mx = v;
                #pragma unroll
                for (int s = 1; s < NS; ++s) {
                    v = p[s * HW];
                    sm += v; mx = fmaxf(mx, v);
                }
                u = make_float2(sm * 0.04f, mx);
            }
            s_l[rr * SRW + cc] = u;
        }
        __syncthreads();

        // ---- phase 2: conv7x7 + sigmoid on a 1x2 point pair; q4 = mask*blur
        if (tid < NPAIR) {
            const int rr  = tid / 10;
            const int cc0 = (tid % 10) * 2;
            float a0 = 0.f, a1 = 0.f;
            #pragma unroll
            for (int j = 0; j < 7; ++j) {
                const float4* rw =
                    reinterpret_cast<const float4*>(s_l + (rr + j) * SRW + cc0);
                float4 t0 = rw[0], t1 = rw[1], t2 = rw[2], t3 = rw[3];
                const float* waj = wb + j * 7;        // avg-ch weights (s_load)
                const float* wmj = wb + 49 + j * 7;   // max-ch weights (s_load)
                a0 += t0.x*waj[0] + t0.y*wmj[0] + t0.z*waj[1] + t0.w*wmj[1]
                    + t1.x*waj[2] + t1.y*wmj[2] + t1.z*waj[3] + t1.w*wmj[3]
                    + t2.x*waj[4] + t2.y*wmj[4] + t2.z*waj[5] + t2.w*wmj[5]
                    + t3.x*waj[6] + t3.y*wmj[6];
                a1 += t0.z*waj[0] + t0.w*wmj[0]
                    + t1.x*waj[1] + t1.y*wmj[1] + t1.z*waj[2] + t1.w*wmj[2]
                    + t2.x*waj[3] + t2.y*wmj[3] + t2.z*waj[4] + t2.w*wmj[4]
                    + t3.x*waj[5] + t3.y*wmj[5] + t3.z*waj[6] + t3.w*wmj[6];
            }
            const float m0 = 1.f / (1.f + __expf(-a0));
            const float m1 = 1.f / (1.f + __expf(-a1));
            const int gh  = h0 - 2 + rr;
            const int gw0 = w0 - 2 + cc0;            // even; pair is all-in or all-out
            const bool inb = ((unsigned)gh < H) && ((unsigned)gw0 < W);
            const int gi = gh * W + gw0;
            float2 b0 = make_float2(0.f, 0.f), b1 = b0, b2 = b0;
            if (inb) {
                b0 = *reinterpret_cast<const float2*>(&blur_info[(n * NC + 0) * HW + gi]);
                b1 = *reinterpret_cast<const float2*>(&blur_info[(n * NC + 1) * HW + gi]);
                b2 = *reinterpret_cast<const float2*>(&blur_info[(n * NC + 2) * HW + gi]);
            }
            const int qi = rr * MRW + cc0;
            q4[qi]     = make_float4(m0 * b0.x, m0 * b1.x, m0 * b2.x, 0.f);
            q4[qi + 1] = make_float4(m1 * b0.y, m1 * b1.y, m1 * b2.y, 0.f);
        }
        __syncthreads();

        // ---- phase 3: fac from pk registers + 26 b128 q reads (imm offsets)
        {
            const float4* qb = q4 + r * MRW + c;
            const float4 Qc = qb[2 * MRW + 2];
            float f0 = -Qc.x, f1 = -Qc.y, f2 = -Qc.z;
            #pragma unroll
            for (int s = 0; s < NS; ++s) {
                const float4 Q = qb[(s / 5) * MRW + (s % 5)];
                const float v = pk[s];
                f0 += v * Q.x;
                f1 += v * Q.y;
                f2 += v * Q.z;
            }
            facc0 += f0; facc1 += f1; facc2 += f2;
        }
        // next branch: phase-1 writes s_l (not read by phase 3); q4 overwrite
        // happens after next post-phase-1 barrier, which no thread passes
        // until all finish phase 3 -> race-free.
    }

    // ---- epilogue: out = blur + (f_1+f_2+f_3)/3  (blur*(1-m) folded via -q_center)
    const float inv3 = 1.f / 3.f;
    const int gi = (h0 + r) * W + (w0 + c);
    out[(n * NC + 0) * HW + gi] = blur_info[(n * NC + 0) * HW + gi] + facc0 * inv3;
    out[(n * NC + 1) * HW + gi] = blur_info[(n * NC + 1) * HW + gi] + facc1 * inv3;
    out[(n * NC + 2) * HW + gi] = blur_info[(n * NC + 2) * HW + gi] + facc2 * inv3;
}

extern "C" void kernel_launch(void* const* d_in, const int* in_sizes, int n_in,
                              void* d_out, int out_size, void* d_ws, size_t ws_size,
                              hipStream_t stream) {
    const float* blur = (const float*)d_in[0];
    float* out = (float*)d_out;

    dim3 grid(W / TW, H / TH, NIMG);     // 16 x 16 x 16 = 4096 blocks
    reblur_fused<<<grid, NTHREADS, 0, stream>>>(
        blur,
        (const float*)d_in[1], (const float*)d_in[2], (const float*)d_in[3],
        (const float*)d_in[4], (const float*)d_in[5], (const float*)d_in[6],
        out);
}